// Round 9
// baseline (358.160 us; speedup 1.0000x reference)
//
#include <hip/hip_runtime.h>

#define NB   4
#define CH   256
#define CQK  32
#define NPOS 4096
#define KT   128
#define QT   64
#define LOG2E 1.4426950408889634f
#define THR2  10.0f   // defer-rescale threshold in log2 units (P <= 2^10)

typedef __attribute__((ext_vector_type(8))) short bf16x8;
typedef __attribute__((ext_vector_type(4))) float f32x4;
typedef unsigned short u16;
typedef unsigned int   u32;

static __device__ __forceinline__ u16 f2bf(float x) {
    union { float f; u32 u; } c; c.f = x;
    u32 u = c.u + 0x7FFFu + ((c.u >> 16) & 1u);
    return (u16)(u >> 16);
}
static __device__ __forceinline__ u32 pack2(float a, float b) {
    return (u32)f2bf(a) | ((u32)f2bf(b) << 16);
}
static __device__ __forceinline__ u32 cvtpk(float a, float b) {
    u32 r;
    asm("v_cvt_pk_bf16_f32 %0, %1, %2" : "=v"(r) : "v"(a), "v"(b));
    return r;
}
static __device__ __forceinline__ float exp2raw(float x) {
    float r;
    asm("v_exp_f32 %0, %1" : "=v"(r) : "v"(x));
    return r;
}

// ---------------------------------------------------------------------------
// W concat + bf16 convert (unchanged).
// ---------------------------------------------------------------------------
__global__ __launch_bounds__(256) void wcvt_kernel(
    const float* __restrict__ wq, const float* __restrict__ bq,
    const float* __restrict__ wk, const float* __restrict__ bk,
    const float* __restrict__ wv, const float* __restrict__ bv,
    u16* __restrict__ wb, float* __restrict__ bb)
{
    int idx = blockIdx.x * 256 + threadIdx.x;
    int e0 = idx * 4;
    const float* src; int off;
    if (e0 < 32 * 256)      { src = wq; off = e0; }
    else if (e0 < 64 * 256) { src = wk; off = e0 - 32 * 256; }
    else                    { src = wv; off = e0 - 64 * 256; }
    float4 v4 = *(const float4*)(src + off);
    *(uint2*)(wb + e0) = make_uint2(pack2(v4.x, v4.y), pack2(v4.z, v4.w));
    if (idx < 320) {
        float b = idx < 32 ? bq[idx] : (idx < 64 ? bk[idx - 32] : bv[idx - 64]);
        bb[idx] = b;
    }
}

// ---------------------------------------------------------------------------
// MFMA QKV projection (unchanged from R7; Q pre-scaled by log2e).
// ---------------------------------------------------------------------------
__global__ __launch_bounds__(256, 1) void qkv_proj_kernel(
    const float* __restrict__ x, const u16* __restrict__ wb, const float* __restrict__ bb,
    u16* __restrict__ qo, u16* __restrict__ ko, u16* __restrict__ vo)
{
    __shared__ u16 ldsx[32][264];
    const int t  = threadIdx.x;
    const int b  = blockIdx.x >> 7;
    const int n0 = (blockIdx.x & 127) * 32;
    const float* xb = x + (size_t)b * CH * NPOS;

    #pragma unroll
    for (int it = 0; it < 4; ++it) {
        int idx = it * 256 + t;
        int cp = idx >> 3;
        int n4 = (idx & 7) * 4;
        int c  = cp * 2;
        float4 a = *(const float4*)(xb + (size_t)c * NPOS + n0 + n4);
        float4 d = *(const float4*)(xb + (size_t)(c + 1) * NPOS + n0 + n4);
        #pragma unroll
        for (int i = 0; i < 4; ++i) {
            int n = n4 + i;
            u32 pv = pack2(((const float*)&a)[i], ((const float*)&d)[i]);
            *(u32*)((char*)ldsx + n * 528 + ((c * 2) ^ ((n & 7) << 4))) = pv;
        }
    }
    __syncthreads();

    const int w = t >> 6, lane = t & 63, g8 = lane >> 4, l16 = lane & 15;

    bf16x8 bf[2][8];
    #pragma unroll
    for (int ns = 0; ns < 2; ++ns) {
        int n = ns * 16 + l16;
        const char* rowp = (const char*)ldsx + n * 528;
        int swz = (n & 7) << 4;
        #pragma unroll
        for (int ks = 0; ks < 8; ++ks)
            bf[ns][ks] = *(const bf16x8*)(rowp + ((ks * 64 + g8 * 16) ^ swz));
    }

    u16* qdst = qo + (size_t)b * NPOS * CQK;
    u16* kdst = ko + (size_t)b * NPOS * CQK;
    u16* vdst = vo + (size_t)b * CH * NPOS;

    bf16x8 afA[8], afB[8];
    #pragma unroll
    for (int ks = 0; ks < 8; ++ks)
        afA[ks] = *(const bf16x8*)(wb + (w * 5 * 16 + l16) * 256 + ks * 32 + g8 * 8);

    #pragma unroll
    for (int j = 0; j < 5; ++j) {
        int ot = w * 5 + j;
        bf16x8* afc = (j & 1) ? afB : afA;
        bf16x8* afn = (j & 1) ? afA : afB;
        if (j + 1 < 5) {
            int otn = ot + 1;
            #pragma unroll
            for (int ks = 0; ks < 8; ++ks)
                afn[ks] = *(const bf16x8*)(wb + (otn * 16 + l16) * 256 + ks * 32 + g8 * 8);
        }
        f32x4 acc[2];
        acc[0] = (f32x4){0.f, 0.f, 0.f, 0.f};
        acc[1] = (f32x4){0.f, 0.f, 0.f, 0.f};
        #pragma unroll
        for (int ks = 0; ks < 8; ++ks) {
            acc[0] = __builtin_amdgcn_mfma_f32_16x16x32_bf16(afc[ks], bf[0][ks], acc[0], 0, 0, 0);
            acc[1] = __builtin_amdgcn_mfma_f32_16x16x32_bf16(afc[ks], bf[1][ks], acc[1], 0, 0, 0);
        }
        float4 bias = *(const float4*)(bb + ot * 16 + g8 * 4);

        if (ot < 4) {
            u16* dst = (ot < 2 ? qdst : kdst);
            float scl = (ot < 2) ? LOG2E : 1.0f;
            int ob = (ot & 1) * 16 + g8 * 4;
            #pragma unroll
            for (int ns = 0; ns < 2; ++ns) {
                int n = n0 + ns * 16 + l16;
                u32 lo = pack2((acc[ns][0] + bias.x) * scl, (acc[ns][1] + bias.y) * scl);
                u32 hi = pack2((acc[ns][2] + bias.z) * scl, (acc[ns][3] + bias.w) * scl);
                *(uint2*)(dst + (size_t)n * CQK + ob) = make_uint2(lo, hi);
            }
        } else {
            int orow = (ot - 4) * 16 + g8 * 4;
            const float* bp = (const float*)&bias;
            #pragma unroll
            for (int r = 0; r < 4; ++r)
                #pragma unroll
                for (int ns = 0; ns < 2; ++ns)
                    vdst[(size_t)(orow + r) * NPOS + n0 + ns * 16 + l16] =
                        f2bf(acc[ns][r] + bp[r]);
        }
    }
}

// ---------------------------------------------------------------------------
// Producer/consumer flash attention with KEY-SPLIT for occupancy.
// SPLIT=true: grid 512 (2 blocks/CU -> 4 waves/SIMD), each block does 16
// windows (half the keys) and stores unnormalized acc (f32 [ch][q]) + per-row
// (m,l) to workspace; merge_kernel combines.  SPLIT=false: R7 fallback,
// grid 256, full 32 windows, in-kernel epilogue.
// ---------------------------------------------------------------------------
#define P_OFF   0        // 2 bufs x 4 strips x 16 q x 256B = 32768
#define SC_OFF  32768    // 2 x 64 f32 = 512
#define FL_OFF  33280    // 2 x 16B = 32
#define LL_OFF  33312    // 64 f32 = 256
#define SMEMSZ  33568

template<bool SPLIT>
__global__ __launch_bounds__(512, 4) void attn_kernel(
    const u16* __restrict__ q, const u16* __restrict__ k, const u16* __restrict__ v,
    const float* __restrict__ input, const float* __restrict__ gamma,
    float* __restrict__ out, float* __restrict__ pO, float* __restrict__ pml)
{
    __shared__ __align__(16) char smem[SMEMSZ];
    const int t = threadIdx.x;
    const int w = t >> 6;
    const int lane = t & 63;
    const int g8 = lane >> 4;
    const int l16 = lane & 15;

    constexpr int W = SPLIT ? 16 : 32;          // windows per block
    const int bid = blockIdx.x;
    const int h = SPLIT ? (bid >> 8) : 0;
    const int lb = bid & 255;
    const int b = (lb >> 1) & 3;
    const int tile = ((lb >> 3) << 1) | (lb & 1);
    const int s = b * 64 + tile;
    const int i0 = tile * QT;
    const int kbase = h * 16 * KT;              // 0 or 2048

    const u16* kb = k + (size_t)b * NPOS * CQK;
    const u16* vb = v + (size_t)b * CH * NPOS;

    if (w < 4) {
        // ===================== producer =====================
        const int strip = w;
        const u16* qb = q + (size_t)b * NPOS * CQK;
        bf16x8 qf = *(const bf16x8*)(qb + (size_t)(i0 + strip * 16 + l16) * CQK + g8 * 8);
        float mrun = -__builtin_inff(), lrun = 0.f;   // lrun is PER-LANE partial

        bf16x8 kc[8];
        #pragma unroll
        for (int nt = 0; nt < 8; ++nt)
            kc[nt] = *(const bf16x8*)(kb + (size_t)(kbase + nt * 16 + l16) * CQK + g8 * 8);

        auto pbody = [&](int c) {
            f32x4 z = {0.f, 0.f, 0.f, 0.f};
            f32x4 sS[8];
            #pragma unroll
            for (int nt = 0; nt < 8; ++nt)   // S[key nt*16+g8*4+r][query l16]
                sS[nt] = __builtin_amdgcn_mfma_f32_16x16x32_bf16(kc[nt], qf, z, 0, 0, 0);
            // in-place K reload for next window (wraps within this half)
            {
                int j0n = kbase + ((c + 1) & (W - 1)) * KT;
                #pragma unroll
                for (int nt = 0; nt < 8; ++nt)
                    kc[nt] = *(const bf16x8*)(kb + (size_t)(j0n + nt * 16 + l16) * CQK + g8 * 8);
            }
            float mx4[8];
            #pragma unroll
            for (int nt = 0; nt < 8; ++nt)
                mx4[nt] = fmaxf(fmaxf(sS[nt][0], sS[nt][1]), fmaxf(sS[nt][2], sS[nt][3]));
            float m01 = fmaxf(fmaxf(mx4[0], mx4[1]), fmaxf(mx4[2], mx4[3]));
            float m23 = fmaxf(fmaxf(mx4[4], mx4[5]), fmaxf(mx4[6], mx4[7]));
            float lmax = fmaxf(m01, m23);

            const int buf = c & 1;
            float sc = 1.0f;
            u32 flagval = 0u;
            if (__any(lmax > mrun + THR2)) {          // rare slow path
                float mxx = fmaxf(lmax, __shfl_xor(lmax, 16));
                mxx = fmaxf(mxx, __shfl_xor(mxx, 32));
                mxx = fmaxf(mxx, mrun);
                sc = exp2raw(mrun - mxx);             // exp2(-inf)=0 first time
                mrun = mxx;
                lrun *= sc;
                flagval = 1u;
            }
            if (g8 == 0)
                *(float*)(smem + SC_OFF + buf * 256 + (strip * 16 + l16) * 4) = sc;

            float p[8][4];
            float ls0 = 0.f, ls1 = 0.f;
            #pragma unroll
            for (int nt = 0; nt < 8; ++nt) {
                float a0 = exp2raw(sS[nt][0] - mrun);
                float a1 = exp2raw(sS[nt][1] - mrun);
                float a2 = exp2raw(sS[nt][2] - mrun);
                float a3 = exp2raw(sS[nt][3] - mrun);
                p[nt][0] = a0; p[nt][1] = a1; p[nt][2] = a2; p[nt][3] = a3;
                if (nt & 1) ls1 += (a0 + a1) + (a2 + a3);
                else        ls0 += (a0 + a1) + (a2 + a3);
            }
            lrun += ls0 + ls1;                        // per-lane partial only

            char* pb = smem + P_OFF + buf * 16384 + strip * 4096 + l16 * 256;
            int swz = (l16 & 7) << 4;
            #pragma unroll
            for (int nt = 0; nt < 8; ++nt) {
                u32 r0 = cvtpk(p[nt][0], p[nt][1]);
                u32 r1 = cvtpk(p[nt][2], p[nt][3]);
                *(uint2*)(pb + ((nt * 32 + g8 * 8) ^ swz)) = make_uint2(r0, r1);
            }
            if (lane == 0)
                *(u32*)(smem + FL_OFF + buf * 16 + strip * 4) = flagval;
            asm volatile("s_waitcnt lgkmcnt(0)" ::: "memory");
        };

        pbody(0);                                // window 0 before first barrier
        for (int jc = 0; jc < W; jc += 2) {
            __builtin_amdgcn_s_barrier();        // publish P[jc]
            asm volatile("" ::: "memory");
            pbody(jc + 1);                       // overlaps consumers' PV(jc)
            __builtin_amdgcn_s_barrier();        // publish P[jc+1]
            asm volatile("" ::: "memory");
            if (jc + 2 < W) pbody(jc + 2);
        }
        // reduce per-lane l partials across g8 groups ONCE
        lrun += __shfl_xor(lrun, 16);
        lrun += __shfl_xor(lrun, 32);
        if (SPLIT) {
            if (g8 == 0) {
                float2 ml = make_float2(mrun, lrun);
                ((float2*)pml)[(size_t)(h * 256 + s) * 64 + strip * 16 + l16] = ml;
            }
        } else {
            if (g8 == 0)
                *(float*)(smem + LL_OFF + (strip * 16 + l16) * 4) = lrun;
            __syncthreads();
        }
    } else {
        // ===================== consumer =====================
        const int ch0 = (w - 4) * 64;
        bf16x8 vc[16];
        #pragma unroll
        for (int ct = 0; ct < 4; ++ct)
            #pragma unroll
            for (int ks = 0; ks < 4; ++ks)
                vc[ct * 4 + ks] = *(const bf16x8*)(vb + (size_t)(ch0 + ct * 16 + l16) * NPOS
                                                   + kbase + ks * 32 + g8 * 8);
        f32x4 acc[4][4];
        #pragma unroll
        for (int mt = 0; mt < 4; ++mt)
            #pragma unroll
            for (int ct = 0; ct < 4; ++ct)
                acc[mt][ct] = (f32x4){0.f, 0.f, 0.f, 0.f};

        auto cbody = [&](int jc) {
            const int buf = jc & 1;
            __builtin_amdgcn_s_barrier();        // P[jc] visible
            asm volatile("" ::: "memory");
            __builtin_amdgcn_sched_barrier(0);
            uint4 fl = *(const uint4*)(smem + FL_OFF + buf * 16);
            bf16x8 pa[4][4];
            int swz = (l16 & 7) << 4;
            #pragma unroll
            for (int mt = 0; mt < 4; ++mt) {
                const char* pb = smem + P_OFF + buf * 16384 + mt * 4096 + l16 * 256;
                #pragma unroll
                for (int ks = 0; ks < 4; ++ks)
                    pa[mt][ks] = *(const bf16x8*)(pb + ((ks * 64 + g8 * 16) ^ swz));
            }
            if (fl.x | fl.y | fl.z | fl.w) {
                #pragma unroll
                for (int mt = 0; mt < 4; ++mt) {
                    f32x4 ss = *(const f32x4*)(smem + SC_OFF + buf * 256 + (mt * 16 + g8 * 4) * 4);
                    #pragma unroll
                    for (int ct = 0; ct < 4; ++ct) acc[mt][ct] *= ss;
                }
            }
            const int j0n = kbase + ((jc + 1) & (W - 1)) * KT;
            __builtin_amdgcn_s_setprio(1);
            #pragma unroll
            for (int ct = 0; ct < 4; ++ct) {
                #pragma unroll
                for (int mt = 0; mt < 4; ++mt)
                    #pragma unroll
                    for (int ks = 0; ks < 4; ++ks)
                        acc[mt][ct] = __builtin_amdgcn_mfma_f32_16x16x32_bf16(
                            pa[mt][ks], vc[ct * 4 + ks], acc[mt][ct], 0, 0, 0);
                #pragma unroll
                for (int ks = 0; ks < 4; ++ks)
                    vc[ct * 4 + ks] = *(const bf16x8*)(vb + (size_t)(ch0 + ct * 16 + l16) * NPOS
                                                       + j0n + ks * 32 + g8 * 8);
            }
            __builtin_amdgcn_s_setprio(0);
        };

        for (int jc = 0; jc < W; ++jc) cbody(jc);

        if (SPLIT) {
            // dump unnormalized acc to workspace: pO[h][s][ch][q]
            float* po = pO + ((size_t)(h * 256 + s) * 256) * 64;
            #pragma unroll
            for (int mt = 0; mt < 4; ++mt)
                #pragma unroll
                for (int ct = 0; ct < 4; ++ct) {
                    int ch = ch0 + ct * 16 + l16;
                    int qi = mt * 16 + g8 * 4;
                    *(f32x4*)(po + (size_t)ch * 64 + qi) = acc[mt][ct];
                }
        } else {
            __syncthreads();                      // LL ready
            f32x4 linv[4];
            #pragma unroll
            for (int mt = 0; mt < 4; ++mt) {
                f32x4 lv = *(const f32x4*)(smem + LL_OFF + (mt * 16 + g8 * 4) * 4);
                f32x4 one = {1.f, 1.f, 1.f, 1.f};
                linv[mt] = one / lv;
            }
            const float gmm = gamma[0];
            const float* inb = input + (size_t)b * CH * NPOS;
            float* ob = out + (size_t)b * CH * NPOS;
            #pragma unroll
            for (int mt = 0; mt < 4; ++mt) {
                #pragma unroll
                for (int ct = 0; ct < 4; ++ct) {
                    f32x4 val = acc[mt][ct] * linv[mt];
                    int ch = ch0 + ct * 16 + l16;
                    size_t gi = (size_t)ch * NPOS + i0 + mt * 16 + g8 * 4;
                    float4 in4 = *(const float4*)(inb + gi);
                    float4 r4;
                    r4.x = gmm * val[0] + in4.x;
                    r4.y = gmm * val[1] + in4.y;
                    r4.z = gmm * val[2] + in4.z;
                    r4.w = gmm * val[3] + in4.w;
                    *(float4*)(ob + gi) = r4;
                }
            }
        }
    }
}

// ---------------------------------------------------------------------------
// Merge two key-halves: out = gamma * (OA*wA + OB*wB)/l + input.
// grid 1024 x 256: block = (s, ch-quarter); thread: n = t&63 (coalesced).
// ---------------------------------------------------------------------------
__global__ __launch_bounds__(256) void merge_kernel(
    const float* __restrict__ pO, const float* __restrict__ pml,
    const float* __restrict__ input, const float* __restrict__ gamma,
    float* __restrict__ out)
{
    const int blk = blockIdx.x;
    const int s = blk >> 2, cq = blk & 3;
    const int t = threadIdx.x;
    const int n = t & 63, sub = t >> 6;
    const int b = s >> 6, tile = s & 63;
    const int i0 = tile * 64;

    const float2 A  = ((const float2*)pml)[(size_t)s * 64 + n];
    const float2 Bv = ((const float2*)pml)[(size_t)(256 + s) * 64 + n];
    float m = fmaxf(A.x, Bv.x);
    float wA = exp2f(A.x - m), wB = exp2f(Bv.x - m);
    float inv = 1.0f / (A.y * wA + Bv.y * wB);
    wA *= inv; wB *= inv;
    const float g = gamma[0];

    #pragma unroll 4
    for (int cc = 0; cc < 16; ++cc) {
        int ch = cq * 64 + sub * 16 + cc;
        size_t pidx = ((size_t)s * 256 + ch) * 64 + n;
        float oA = pO[pidx];
        float oB = pO[pidx + (size_t)4194304];   // 256*256*64
        size_t gi = ((size_t)b * 256 + ch) * 4096 + i0 + n;
        out[gi] = g * (oA * wA + oB * wB) + input[gi];
    }
}

// ---------------------------------------------------------------------------
extern "C" void kernel_launch(void* const* d_in, const int* in_sizes, int n_in,
                              void* d_out, int out_size, void* d_ws, size_t ws_size,
                              hipStream_t stream) {
    const float* input = (const float*)d_in[0];
    const float* wq    = (const float*)d_in[1];
    const float* bq    = (const float*)d_in[2];
    const float* wk    = (const float*)d_in[3];
    const float* bk    = (const float*)d_in[4];
    const float* wv    = (const float*)d_in[5];
    const float* bv    = (const float*)d_in[6];
    const float* gamma = (const float*)d_in[7];
    float* out = (float*)d_out;

    const size_t qk_elems = (size_t)NB * NPOS * CQK;   // 524288
    const size_t v_elems  = (size_t)NB * CH * NPOS;    // 4194304
    const size_t w_elems  = 320 * 256;                 // 81920
    size_t base_need = (2 * qk_elems + v_elems + w_elems) * sizeof(u16) + 320 * sizeof(float);
    if (ws_size < base_need) return;

    u16* qw = (u16*)d_ws;
    u16* kw = qw + qk_elems;
    u16* vw = kw + qk_elems;
    u16* wb = vw + v_elems;
    float* bbuf = (float*)(wb + w_elems);

    size_t po_off = (base_need + 255) & ~(size_t)255;
    const size_t pO_elems  = (size_t)2 * 256 * 256 * 64;   // 8388608 f32 = 32MB
    const size_t pml_elems = (size_t)2 * 256 * 64 * 2;     // 65536 f32
    size_t split_need = po_off + (pO_elems + pml_elems) * sizeof(float);
    bool split = (ws_size >= split_need);

    float* pO  = (float*)((char*)d_ws + po_off);
    float* pml = pO + pO_elems;

    wcvt_kernel<<<dim3(80), dim3(256), 0, stream>>>(wq, bq, wk, bk, wv, bv, wb, bbuf);
    qkv_proj_kernel<<<dim3(NB * (NPOS / 32)), dim3(256), 0, stream>>>(input, wb, bbuf, qw, kw, vw);

    if (split) {
        attn_kernel<true><<<dim3(512), dim3(512), 0, stream>>>(
            qw, kw, vw, input, gamma, out, pO, pml);
        merge_kernel<<<dim3(1024), dim3(256), 0, stream>>>(pO, pml, input, gamma, out);
    } else {
        attn_kernel<false><<<dim3(256), dim3(512), 0, stream>>>(
            qw, kw, vw, input, gamma, out, pO, pml);
    }
}

// Round 10
// 112.321 us; speedup vs baseline: 3.1887x; 3.1887x over previous
//
#include <hip/hip_runtime.h>

#define NB   4
#define CH   256
#define CQK  32
#define NPOS 4096
#define KT   64
#define QT   64
#define LOG2E 1.4426950408889634f
#define THR2  10.0f   // defer-rescale threshold in log2 units (P <= 2^10)

typedef __attribute__((ext_vector_type(8))) short bf16x8;
typedef __attribute__((ext_vector_type(4))) float f32x4;
typedef unsigned short u16;
typedef unsigned int   u32;

static __device__ __forceinline__ u16 f2bf(float x) {
    union { float f; u32 u; } c; c.f = x;
    u32 u = c.u + 0x7FFFu + ((c.u >> 16) & 1u);
    return (u16)(u >> 16);
}
static __device__ __forceinline__ u32 pack2(float a, float b) {
    return (u32)f2bf(a) | ((u32)f2bf(b) << 16);
}
static __device__ __forceinline__ u32 cvtpk(float a, float b) {
    u32 r;
    asm("v_cvt_pk_bf16_f32 %0, %1, %2" : "=v"(r) : "v"(a), "v"(b));
    return r;
}
static __device__ __forceinline__ float exp2raw(float x) {
    float r;
    asm("v_exp_f32 %0, %1" : "=v"(r) : "v"(x));
    return r;
}

// ---------------------------------------------------------------------------
// W concat + bf16 convert (unchanged).
// ---------------------------------------------------------------------------
__global__ __launch_bounds__(256) void wcvt_kernel(
    const float* __restrict__ wq, const float* __restrict__ bq,
    const float* __restrict__ wk, const float* __restrict__ bk,
    const float* __restrict__ wv, const float* __restrict__ bv,
    u16* __restrict__ wb, float* __restrict__ bb)
{
    int idx = blockIdx.x * 256 + threadIdx.x;
    int e0 = idx * 4;
    const float* src; int off;
    if (e0 < 32 * 256)      { src = wq; off = e0; }
    else if (e0 < 64 * 256) { src = wk; off = e0 - 32 * 256; }
    else                    { src = wv; off = e0 - 64 * 256; }
    float4 v4 = *(const float4*)(src + off);
    *(uint2*)(wb + e0) = make_uint2(pack2(v4.x, v4.y), pack2(v4.z, v4.w));
    if (idx < 320) {
        float b = idx < 32 ? bq[idx] : (idx < 64 ? bk[idx - 32] : bv[idx - 64]);
        bb[idx] = b;
    }
}

// ---------------------------------------------------------------------------
// MFMA QKV projection (unchanged; Q pre-scaled by log2e).
// ---------------------------------------------------------------------------
__global__ __launch_bounds__(256, 1) void qkv_proj_kernel(
    const float* __restrict__ x, const u16* __restrict__ wb, const float* __restrict__ bb,
    u16* __restrict__ qo, u16* __restrict__ ko, u16* __restrict__ vo)
{
    __shared__ u16 ldsx[32][264];
    const int t  = threadIdx.x;
    const int b  = blockIdx.x >> 7;
    const int n0 = (blockIdx.x & 127) * 32;
    const float* xb = x + (size_t)b * CH * NPOS;

    #pragma unroll
    for (int it = 0; it < 4; ++it) {
        int idx = it * 256 + t;
        int cp = idx >> 3;
        int n4 = (idx & 7) * 4;
        int c  = cp * 2;
        float4 a = *(const float4*)(xb + (size_t)c * NPOS + n0 + n4);
        float4 d = *(const float4*)(xb + (size_t)(c + 1) * NPOS + n0 + n4);
        #pragma unroll
        for (int i = 0; i < 4; ++i) {
            int n = n4 + i;
            u32 pv = pack2(((const float*)&a)[i], ((const float*)&d)[i]);
            *(u32*)((char*)ldsx + n * 528 + ((c * 2) ^ ((n & 7) << 4))) = pv;
        }
    }
    __syncthreads();

    const int w = t >> 6, lane = t & 63, g8 = lane >> 4, l16 = lane & 15;

    bf16x8 bf[2][8];
    #pragma unroll
    for (int ns = 0; ns < 2; ++ns) {
        int n = ns * 16 + l16;
        const char* rowp = (const char*)ldsx + n * 528;
        int swz = (n & 7) << 4;
        #pragma unroll
        for (int ks = 0; ks < 8; ++ks)
            bf[ns][ks] = *(const bf16x8*)(rowp + ((ks * 64 + g8 * 16) ^ swz));
    }

    u16* qdst = qo + (size_t)b * NPOS * CQK;
    u16* kdst = ko + (size_t)b * NPOS * CQK;
    u16* vdst = vo + (size_t)b * CH * NPOS;

    bf16x8 afA[8], afB[8];
    #pragma unroll
    for (int ks = 0; ks < 8; ++ks)
        afA[ks] = *(const bf16x8*)(wb + (w * 5 * 16 + l16) * 256 + ks * 32 + g8 * 8);

    #pragma unroll
    for (int j = 0; j < 5; ++j) {
        int ot = w * 5 + j;
        bf16x8* afc = (j & 1) ? afB : afA;
        bf16x8* afn = (j & 1) ? afA : afB;
        if (j + 1 < 5) {
            int otn = ot + 1;
            #pragma unroll
            for (int ks = 0; ks < 8; ++ks)
                afn[ks] = *(const bf16x8*)(wb + (otn * 16 + l16) * 256 + ks * 32 + g8 * 8);
        }
        f32x4 acc[2];
        acc[0] = (f32x4){0.f, 0.f, 0.f, 0.f};
        acc[1] = (f32x4){0.f, 0.f, 0.f, 0.f};
        #pragma unroll
        for (int ks = 0; ks < 8; ++ks) {
            acc[0] = __builtin_amdgcn_mfma_f32_16x16x32_bf16(afc[ks], bf[0][ks], acc[0], 0, 0, 0);
            acc[1] = __builtin_amdgcn_mfma_f32_16x16x32_bf16(afc[ks], bf[1][ks], acc[1], 0, 0, 0);
        }
        float4 bias = *(const float4*)(bb + ot * 16 + g8 * 4);

        if (ot < 4) {
            u16* dst = (ot < 2 ? qdst : kdst);
            float scl = (ot < 2) ? LOG2E : 1.0f;
            int ob = (ot & 1) * 16 + g8 * 4;
            #pragma unroll
            for (int ns = 0; ns < 2; ++ns) {
                int n = n0 + ns * 16 + l16;
                u32 lo = pack2((acc[ns][0] + bias.x) * scl, (acc[ns][1] + bias.y) * scl);
                u32 hi = pack2((acc[ns][2] + bias.z) * scl, (acc[ns][3] + bias.w) * scl);
                *(uint2*)(dst + (size_t)n * CQK + ob) = make_uint2(lo, hi);
            }
        } else {
            int orow = (ot - 4) * 16 + g8 * 4;
            const float* bp = (const float*)&bias;
            #pragma unroll
            for (int r = 0; r < 4; ++r)
                #pragma unroll
                for (int ns = 0; ns < 2; ++ns)
                    vdst[(size_t)(orow + r) * NPOS + n0 + ns * 16 + l16] =
                        f2bf(acc[ns][r] + bp[r]);
        }
    }
}

// ---------------------------------------------------------------------------
// Producer/consumer flash attention, key-split, register-budgeted for
// 2 blocks/CU (4 waves/SIMD, 128-reg cap).  KT=64.
// SPLIT: grid 512, 32 windows/block, unnormalized acc + (m,l) -> workspace.
// else: grid 256, 64 windows, in-kernel epilogue.
// Consumer: vc[8] (32 regs, in-place reload), pa per-mt (8 regs transient),
// acc[4][4] (64, AGPR-eligible)  -> peak ~118.
// ---------------------------------------------------------------------------
#define P_OFF   0        // 2 bufs x 4 strips x 16 q x 128B = 16384
#define SC_OFF  16384    // 2 x 64 f32 = 512
#define FL_OFF  16896    // 2 x 16B = 32
#define LL_OFF  16928    // 64 f32 = 256
#define SMEMSZ  17184

template<bool SPLIT>
__global__ __launch_bounds__(512, 2) void attn_kernel(
    const u16* __restrict__ q, const u16* __restrict__ k, const u16* __restrict__ v,
    const float* __restrict__ input, const float* __restrict__ gamma,
    float* __restrict__ out, float* __restrict__ pO, float* __restrict__ pml)
{
    __shared__ __align__(16) char smem[SMEMSZ];
    const int t = threadIdx.x;
    const int w = t >> 6;
    const int lane = t & 63;
    const int g8 = lane >> 4;
    const int l16 = lane & 15;

    constexpr int W = SPLIT ? 32 : 64;          // KT=64 windows per block
    const int bid = blockIdx.x;
    const int h = SPLIT ? (bid >> 8) : 0;
    const int lb = bid & 255;
    const int b = (lb >> 1) & 3;
    const int tile = ((lb >> 3) << 1) | (lb & 1);
    const int s = b * 64 + tile;
    const int i0 = tile * QT;
    const int kbase = h * (NPOS / 2);           // 0 or 2048

    const u16* kb = k + (size_t)b * NPOS * CQK;
    const u16* vb = v + (size_t)b * CH * NPOS;

    if (w < 4) {
        // ===================== producer =====================
        const int strip = w;
        const u16* qb = q + (size_t)b * NPOS * CQK;
        bf16x8 qf = *(const bf16x8*)(qb + (size_t)(i0 + strip * 16 + l16) * CQK + g8 * 8);
        float mrun = -__builtin_inff(), lrun = 0.f;   // lrun is PER-LANE partial

        bf16x8 kc[4];
        #pragma unroll
        for (int nt = 0; nt < 4; ++nt)
            kc[nt] = *(const bf16x8*)(kb + (size_t)(kbase + nt * 16 + l16) * CQK + g8 * 8);

        auto pbody = [&](int c) {
            f32x4 z = {0.f, 0.f, 0.f, 0.f};
            f32x4 sS[4];
            #pragma unroll
            for (int nt = 0; nt < 4; ++nt)   // S[key nt*16+g8*4+r][query l16]
                sS[nt] = __builtin_amdgcn_mfma_f32_16x16x32_bf16(kc[nt], qf, z, 0, 0, 0);
            // in-place K reload for next window (wraps within this half)
            {
                int j0n = kbase + ((c + 1) & (W - 1)) * KT;
                #pragma unroll
                for (int nt = 0; nt < 4; ++nt)
                    kc[nt] = *(const bf16x8*)(kb + (size_t)(j0n + nt * 16 + l16) * CQK + g8 * 8);
            }
            float mx4[4];
            #pragma unroll
            for (int nt = 0; nt < 4; ++nt)
                mx4[nt] = fmaxf(fmaxf(sS[nt][0], sS[nt][1]), fmaxf(sS[nt][2], sS[nt][3]));
            float lmax = fmaxf(fmaxf(mx4[0], mx4[1]), fmaxf(mx4[2], mx4[3]));

            const int buf = c & 1;
            float sc = 1.0f;
            u32 flagval = 0u;
            if (__any(lmax > mrun + THR2)) {          // rare slow path
                float mxx = fmaxf(lmax, __shfl_xor(lmax, 16));
                mxx = fmaxf(mxx, __shfl_xor(mxx, 32));
                mxx = fmaxf(mxx, mrun);
                sc = exp2raw(mrun - mxx);             // exp2(-inf)=0 first time
                mrun = mxx;
                lrun *= sc;
                flagval = 1u;
            }
            if (g8 == 0)
                *(float*)(smem + SC_OFF + buf * 256 + (strip * 16 + l16) * 4) = sc;

            float ls = 0.f;
            char* pb = smem + P_OFF + buf * 8192 + strip * 2048 + l16 * 128;
            int swz = (l16 & 7) << 4;
            #pragma unroll
            for (int nt = 0; nt < 4; ++nt) {
                float a0 = exp2raw(sS[nt][0] - mrun);
                float a1 = exp2raw(sS[nt][1] - mrun);
                float a2 = exp2raw(sS[nt][2] - mrun);
                float a3 = exp2raw(sS[nt][3] - mrun);
                ls += (a0 + a1) + (a2 + a3);
                *(uint2*)(pb + ((nt * 32 + g8 * 8) ^ swz)) =
                    make_uint2(cvtpk(a0, a1), cvtpk(a2, a3));
            }
            lrun += ls;                               // per-lane partial only
            if (lane == 0)
                *(u32*)(smem + FL_OFF + buf * 16 + strip * 4) = flagval;
            asm volatile("s_waitcnt lgkmcnt(0)" ::: "memory");
        };

        pbody(0);                                // window 0 before first barrier
        for (int jc = 0; jc < W; jc += 2) {
            __builtin_amdgcn_s_barrier();        // publish P[jc]
            asm volatile("" ::: "memory");
            pbody(jc + 1);                       // overlaps consumers' PV(jc)
            __builtin_amdgcn_s_barrier();        // publish P[jc+1]
            asm volatile("" ::: "memory");
            if (jc + 2 < W) pbody(jc + 2);
        }
        // reduce per-lane l partials across g8 groups ONCE
        lrun += __shfl_xor(lrun, 16);
        lrun += __shfl_xor(lrun, 32);
        if (SPLIT) {
            if (g8 == 0) {
                float2 ml = make_float2(mrun, lrun);
                ((float2*)pml)[(size_t)(h * 256 + s) * 64 + strip * 16 + l16] = ml;
            }
        } else {
            if (g8 == 0)
                *(float*)(smem + LL_OFF + (strip * 16 + l16) * 4) = lrun;
            __syncthreads();
        }
    } else {
        // ===================== consumer =====================
        const int ch0 = (w - 4) * 64;
        bf16x8 vc[8];
        #pragma unroll
        for (int ct = 0; ct < 4; ++ct)
            #pragma unroll
            for (int ks = 0; ks < 2; ++ks)
                vc[ct * 2 + ks] = *(const bf16x8*)(vb + (size_t)(ch0 + ct * 16 + l16) * NPOS
                                                   + kbase + ks * 32 + g8 * 8);
        f32x4 acc[4][4];
        #pragma unroll
        for (int mt = 0; mt < 4; ++mt)
            #pragma unroll
            for (int ct = 0; ct < 4; ++ct)
                acc[mt][ct] = (f32x4){0.f, 0.f, 0.f, 0.f};

        auto cbody = [&](int jc) {
            const int buf = jc & 1;
            __builtin_amdgcn_s_barrier();        // P[jc] visible
            asm volatile("" ::: "memory");
            __builtin_amdgcn_sched_barrier(0);
            uint4 fl = *(const uint4*)(smem + FL_OFF + buf * 16);
            if (fl.x | fl.y | fl.z | fl.w) {
                #pragma unroll
                for (int mt = 0; mt < 4; ++mt) {
                    f32x4 ss = *(const f32x4*)(smem + SC_OFF + buf * 256 + (mt * 16 + g8 * 4) * 4);
                    #pragma unroll
                    for (int ct = 0; ct < 4; ++ct) acc[mt][ct] *= ss;
                }
            }
            int swz = (l16 & 7) << 4;
            __builtin_amdgcn_s_setprio(1);
            #pragma unroll
            for (int mt = 0; mt < 4; ++mt) {     // pa loaded per-mt: 8 regs live
                const char* pb = smem + P_OFF + buf * 8192 + mt * 2048 + l16 * 128;
                bf16x8 pa0 = *(const bf16x8*)(pb + ((g8 * 16) ^ swz));
                bf16x8 pa1 = *(const bf16x8*)(pb + ((64 + g8 * 16) ^ swz));
                #pragma unroll
                for (int ct = 0; ct < 4; ++ct) {
                    acc[mt][ct] = __builtin_amdgcn_mfma_f32_16x16x32_bf16(pa0, vc[ct * 2 + 0], acc[mt][ct], 0, 0, 0);
                    acc[mt][ct] = __builtin_amdgcn_mfma_f32_16x16x32_bf16(pa1, vc[ct * 2 + 1], acc[mt][ct], 0, 0, 0);
                }
            }
            __builtin_amdgcn_s_setprio(0);
            // in-place V reload for next window (consumed after next barrier)
            {
                int j0n = kbase + ((jc + 1) & (W - 1)) * KT;
                #pragma unroll
                for (int ct = 0; ct < 4; ++ct)
                    #pragma unroll
                    for (int ks = 0; ks < 2; ++ks)
                        vc[ct * 2 + ks] = *(const bf16x8*)(vb + (size_t)(ch0 + ct * 16 + l16) * NPOS
                                                           + j0n + ks * 32 + g8 * 8);
            }
        };

        for (int jc = 0; jc < W; ++jc) cbody(jc);

        if (SPLIT) {
            // dump unnormalized acc: pO[h][s][ch][q]
            float* po = pO + ((size_t)(h * 256 + s) * 256) * 64;
            #pragma unroll
            for (int mt = 0; mt < 4; ++mt)
                #pragma unroll
                for (int ct = 0; ct < 4; ++ct) {
                    int ch = ch0 + ct * 16 + l16;
                    int qi = mt * 16 + g8 * 4;
                    *(f32x4*)(po + (size_t)ch * 64 + qi) = acc[mt][ct];
                }
        } else {
            __syncthreads();                      // LL ready
            f32x4 linv[4];
            #pragma unroll
            for (int mt = 0; mt < 4; ++mt) {
                f32x4 lv = *(const f32x4*)(smem + LL_OFF + (mt * 16 + g8 * 4) * 4);
                f32x4 one = {1.f, 1.f, 1.f, 1.f};
                linv[mt] = one / lv;
            }
            const float gmm = gamma[0];
            const float* inb = input + (size_t)b * CH * NPOS;
            float* ob = out + (size_t)b * CH * NPOS;
            #pragma unroll
            for (int mt = 0; mt < 4; ++mt) {
                #pragma unroll
                for (int ct = 0; ct < 4; ++ct) {
                    f32x4 val = acc[mt][ct] * linv[mt];
                    int ch = ch0 + ct * 16 + l16;
                    size_t gi = (size_t)ch * NPOS + i0 + mt * 16 + g8 * 4;
                    float4 in4 = *(const float4*)(inb + gi);
                    float4 r4;
                    r4.x = gmm * val[0] + in4.x;
                    r4.y = gmm * val[1] + in4.y;
                    r4.z = gmm * val[2] + in4.z;
                    r4.w = gmm * val[3] + in4.w;
                    *(float4*)(ob + gi) = r4;
                }
            }
        }
    }
}

// ---------------------------------------------------------------------------
// Merge two key-halves: out = gamma * (OA*wA + OB*wB) + input.
// grid 1024 x 256: block = (s, ch-quarter); thread: n = t&63 (coalesced).
// ---------------------------------------------------------------------------
__global__ __launch_bounds__(256) void merge_kernel(
    const float* __restrict__ pO, const float* __restrict__ pml,
    const float* __restrict__ input, const float* __restrict__ gamma,
    float* __restrict__ out)
{
    const int blk = blockIdx.x;
    const int s = blk >> 2, cq = blk & 3;
    const int t = threadIdx.x;
    const int n = t & 63, sub = t >> 6;
    const int b = s >> 6, tile = s & 63;
    const int i0 = tile * 64;

    const float2 A  = ((const float2*)pml)[(size_t)s * 64 + n];
    const float2 Bv = ((const float2*)pml)[(size_t)(256 + s) * 64 + n];
    float m = fmaxf(A.x, Bv.x);
    float wA = exp2f(A.x - m), wB = exp2f(Bv.x - m);
    float inv = 1.0f / (A.y * wA + Bv.y * wB);
    wA *= inv; wB *= inv;
    const float g = gamma[0];

    #pragma unroll 4
    for (int cc = 0; cc < 16; ++cc) {
        int ch = cq * 64 + sub * 16 + cc;
        size_t pidx = ((size_t)s * 256 + ch) * 64 + n;
        float oA = pO[pidx];
        float oB = pO[pidx + (size_t)4194304];   // 256*256*64
        size_t gi = ((size_t)b * 256 + ch) * 4096 + i0 + n;
        out[gi] = g * (oA * wA + oB * wB) + input[gi];
    }
}

// ---------------------------------------------------------------------------
extern "C" void kernel_launch(void* const* d_in, const int* in_sizes, int n_in,
                              void* d_out, int out_size, void* d_ws, size_t ws_size,
                              hipStream_t stream) {
    const float* input = (const float*)d_in[0];
    const float* wq    = (const float*)d_in[1];
    const float* bq    = (const float*)d_in[2];
    const float* wk    = (const float*)d_in[3];
    const float* bk    = (const float*)d_in[4];
    const float* wv    = (const float*)d_in[5];
    const float* bv    = (const float*)d_in[6];
    const float* gamma = (const float*)d_in[7];
    float* out = (float*)d_out;

    const size_t qk_elems = (size_t)NB * NPOS * CQK;   // 524288
    const size_t v_elems  = (size_t)NB * CH * NPOS;    // 4194304
    const size_t w_elems  = 320 * 256;                 // 81920
    size_t base_need = (2 * qk_elems + v_elems + w_elems) * sizeof(u16) + 320 * sizeof(float);
    if (ws_size < base_need) return;

    u16* qw = (u16*)d_ws;
    u16* kw = qw + qk_elems;
    u16* vw = kw + qk_elems;
    u16* wb = vw + v_elems;
    float* bbuf = (float*)(wb + w_elems);

    size_t po_off = (base_need + 255) & ~(size_t)255;
    const size_t pO_elems  = (size_t)2 * 256 * 256 * 64;   // 32 MB
    const size_t pml_elems = (size_t)2 * 256 * 64 * 2;
    size_t split_need = po_off + (pO_elems + pml_elems) * sizeof(float);
    bool split = (ws_size >= split_need);

    float* pO  = (float*)((char*)d_ws + po_off);
    float* pml = pO + pO_elems;

    wcvt_kernel<<<dim3(80), dim3(256), 0, stream>>>(wq, bq, wk, bk, wv, bv, wb, bbuf);
    qkv_proj_kernel<<<dim3(NB * (NPOS / 32)), dim3(256), 0, stream>>>(input, wb, bbuf, qw, kw, vw);

    if (split) {
        attn_kernel<true><<<dim3(512), dim3(512), 0, stream>>>(
            qw, kw, vw, input, gamma, out, pO, pml);
        merge_kernel<<<dim3(1024), dim3(256), 0, stream>>>(pO, pml, input, gamma, out);
    } else {
        attn_kernel<false><<<dim3(256), dim3(512), 0, stream>>>(
            qw, kw, vw, input, gamma, out, pO, pml);
    }
}